// Round 1
// 26049.139 us; speedup vs baseline: 1.4849x; 1.4849x over previous
//
#include <hip/hip_runtime.h>

// FFJORD density on MI355X (gfx950). B=65536 rows, DIM=128, HID=512, 32 RK4 steps x 4 evals.
// Round 3: fuse K2..K5 into one persistent-tile kernel (kbc_k). Per stage only 2 dispatches:
//   K1   : h1 = tanh(zs @ W1z + t*w1t + b1)                  (global, needed twice later)
//   KBC  : phase A  h2 = tanh(h1 @ W2 + b2)    -> LDS (64x512 panel, stride 524)
//          phase B  f  = h2 @ W3 + b3          -> RK4 z/accf/zs epilogue (A from LDS, no staging)
//          phase C  Hs <- g2 = g3*(1-h2^2)      (in-place LDS, vectorized g3 reads)
//          phase D  Hs <- g2 @ W2^T             (A from LDS, in-place overwrite after barrier)
//          phase D2 Hs *= (1-h1^2)              (vectorized h1 reads)  => g1
//          phase E  vJ = g1 @ W1z^T; div = rowsum(vJ*v); accd/lp update
// Eliminates h2/g2/g1 global round-trips, the 1-block/CU N=128 kernels (old K3/K5), and
// ~768 dispatches/run. LDS 76.3 KB/block -> 2 blocks/CU (8 waves/CU) for cross-block overlap.

#define DIMV 128
#define HIDV 512
#define HS_STRIDE 524  // 64-row h2/g2/g1 panel stride (shorts): 1048B/row == 6 banks mod 32
                       // -> quad rows (stride 4) land on bank shifts {0,24,16,8}: 2-way max.

typedef float  floatx4 __attribute__((ext_vector_type(4)));
typedef short  short8  __attribute__((ext_vector_type(8)));

static __device__ __forceinline__ unsigned short f2bf(float x) {
    union { float f; unsigned int u; } c; c.f = x;
    unsigned int u = c.u;
    u += 0x7FFFu + ((u >> 16) & 1u);   // round-to-nearest-even
    return (unsigned short)(u >> 16);
}
static __device__ __forceinline__ float bf2f(unsigned short h) {
    union { unsigned int u; float f; } c; c.u = ((unsigned int)h) << 16;
    return c.f;
}
static __device__ __forceinline__ float fast_tanh(float x) {
    x = fminf(8.0f, fmaxf(-8.0f, x));
    float e = exp2f(x * 2.8853900817779268f);            // exp(2x)
    return (e - 1.0f) * __builtin_amdgcn_rcpf(e + 1.0f); // (e-1)/(e+1)
}

// ---- weight packing: dst[(k>>3)*N*8 + n*8 + (k&7)] = bf16(W[k][n]) ------------
__global__ void pack_kernel(const float* __restrict__ src, unsigned short* __restrict__ dst,
                            int K, int N, int ld, int transpose) {
    int i = blockIdx.x * 256 + threadIdx.x;
    if (i >= K * N) return;
    int j  = i & 7;
    int n  = (i >> 3) % N;
    int k8 = (i >> 3) / N;
    int k  = k8 * 8 + j;
    float v = transpose ? src[n * ld + k] : src[k * ld + n];
    dst[i] = f2bf(v);
}

// ---- per-chunk init: z = x (fp32), zs = bf16(x), lp = 0 -----------------------
__global__ void init_k(const float* __restrict__ x, float* __restrict__ z,
                       unsigned short* __restrict__ zs, float* __restrict__ lp,
                       int n, int nrows) {
    int i = blockIdx.x * 256 + threadIdx.x;
    if (i < n) { float val = x[i]; z[i] = val; zs[i] = f2bf(val); }
    if (i < nrows) lp[i] = 0.0f;
}

#define PROD_BF16 0
#define PROD_V    1
#define EPI_H1   0
#define EPI_G3   1

struct GArgs {
    const float* v;            // fp32 probe (chunk ptr) [C,128]
    const unsigned short* A;   // bf16 A input
    const unsigned short* Wp;  // packed bf16 weights
    const float* bias;
    const float* w1t;          // W1 row 128 (t coefficients)
    unsigned short* out0;      // bf16 output
    float t;
};

// K1 / g3 producer. Tile: 128 rows x (NFRAG*64) cols per WG; 4 waves.
// LDS A-chunk: 128 rows x 64 k, stride 72 bf16 (2-way bank alias only).
template<int KDIM, int NDIM, int NFRAG, int PROD, int EPI>
__global__ __launch_bounds__(256, 2) void gemm_k(GArgs p) {
    __shared__ __align__(16) unsigned short As[128 * 72];
    const int tid  = threadIdx.x;
    const int wave = tid >> 6, lane = tid & 63;
    const int quad = lane >> 4, l16 = lane & 15;
    const int row0 = blockIdx.x * 128;
    const int colw = blockIdx.y * (NFRAG * 64) + wave * (NFRAG * 16);

    floatx4 acc[8][NFRAG];
    #pragma unroll
    for (int m = 0; m < 8; ++m)
        #pragma unroll
        for (int f = 0; f < NFRAG; ++f) {
            floatx4 zz = {0.f, 0.f, 0.f, 0.f};
            acc[m][f] = zz;
        }

    for (int k0 = 0; k0 < KDIM; k0 += 64) {
        __syncthreads();
        {   // ---- stage A chunk: 128 rows x 64 k into LDS ----
            const int r  = tid >> 3;
            const int cc = (tid & 7) << 3;
            #pragma unroll
            for (int i = 0; i < 4; ++i) {
                const int rr = r + (i << 5);
                const size_t base = (size_t)(row0 + rr) * KDIM + k0 + cc;
                if constexpr (PROD == PROD_BF16) {
                    const short8 val = *reinterpret_cast<const short8*>(&p.A[base]);
                    *reinterpret_cast<short8*>(&As[rr * 72 + cc]) = val;
                } else { // PROD_V: fp32 -> bf16 on the fly
                    float vals[8];
                    *(float4*)&vals[0] = *(const float4*)&p.v[base];
                    *(float4*)&vals[4] = *(const float4*)&p.v[base + 4];
                    short8 sv;
                    #pragma unroll
                    for (int j = 0; j < 8; ++j) sv[j] = (short)f2bf(vals[j]);
                    *reinterpret_cast<short8*>(&As[rr * 72 + cc]) = sv;
                }
            }
        }
        __syncthreads();
        #pragma unroll
        for (int kt = 0; kt < 2; ++kt) {
            const int k8 = (k0 >> 3) + (kt << 2) + quad;
            short8 b[NFRAG];
            #pragma unroll
            for (int f = 0; f < NFRAG; ++f)
                b[f] = *reinterpret_cast<const short8*>(
                    &p.Wp[((size_t)k8 * NDIM + colw + (f << 4) + l16) << 3]);
            #pragma unroll
            for (int m = 0; m < 8; ++m) {
                const short8 a = *reinterpret_cast<const short8*>(
                    &As[(m * 16 + l16) * 72 + (kt << 5) + (quad << 3)]);
                #pragma unroll
                for (int f = 0; f < NFRAG; ++f)
                    acc[m][f] = __builtin_amdgcn_mfma_f32_16x16x32_bf16(a, b[f], acc[m][f], 0, 0, 0);
            }
        }
    }

    #pragma unroll
    for (int m = 0; m < 8; ++m)
        #pragma unroll
        for (int f = 0; f < NFRAG; ++f) {
            const int col = colw + (f << 4) + l16;
            float bias = 0.0f;
            if constexpr (EPI == EPI_H1) bias = p.bias[col] + p.t * p.w1t[col];
            #pragma unroll
            for (int r = 0; r < 4; ++r) {
                const int row = row0 + m * 16 + quad * 4 + r;
                const size_t idxN = (size_t)row * NDIM + col;
                float x = acc[m][f][r] + bias;
                if constexpr (EPI == EPI_H1) p.out0[idxN] = f2bf(fast_tanh(x));
                else                         p.out0[idxN] = f2bf(x);
            }
        }
}

// ---- fused stage kernel: K2+K3+K4+K5 -----------------------------------------
struct FArgs {
    const unsigned short* A;      // h1 bf16 [C,512]
    const unsigned short* W2p;    // packed W2    (K=512,N=512)
    const unsigned short* W3p;    // packed W3    (K=512,N=128)
    const unsigned short* W2Tp;   // packed W2^T  (K=512,N=512)
    const unsigned short* W1Tp;   // packed W1z^T (K=512,N=128)
    const unsigned short* g3;     // bf16 [C,512]
    const float* v;               // f32 [C,128]
    const float* b2;
    const float* b3;
    float* z;
    float* accf;
    unsigned short* zs;
    float* accd;
    float* lp;
    float cnext, wrk;
    int s0, s3;
};

__global__ __launch_bounds__(256, 2) void kbc_k(FArgs p) {
    __shared__ __align__(16) unsigned short As[64 * 72];        //  9.2 KB h1 staging
    __shared__ __align__(16) unsigned short Hs[64 * HS_STRIDE]; // 67.1 KB h2/g2/g1 panel
    const int tid  = threadIdx.x;
    const int wave = tid >> 6, lane = tid & 63;
    const int quad = lane >> 4, l16 = lane & 15;
    const int row0 = blockIdx.x * 64;
    const int colw = wave << 7;   // phases A/D: 128 cols per wave

    // ================= phase A: h2 = tanh(h1 @ W2 + b2) -> Hs =================
    floatx4 acc[4][8];
    #pragma unroll
    for (int m = 0; m < 4; ++m)
        #pragma unroll
        for (int f = 0; f < 8; ++f) { floatx4 zz = {0.f,0.f,0.f,0.f}; acc[m][f] = zz; }

    for (int k0 = 0; k0 < 512; k0 += 64) {
        __syncthreads();
        {   // stage 64 rows x 64 k of h1
            const int r  = tid >> 3;
            const int cc = (tid & 7) << 3;
            #pragma unroll
            for (int i = 0; i < 2; ++i) {
                const int rr = r + (i << 5);
                *reinterpret_cast<short8*>(&As[rr * 72 + cc]) =
                    *reinterpret_cast<const short8*>(&p.A[(size_t)(row0 + rr) * 512 + k0 + cc]);
            }
        }
        __syncthreads();
        #pragma unroll
        for (int kt = 0; kt < 2; ++kt) {
            const int k8 = (k0 >> 3) + (kt << 2) + quad;
            short8 b[8];
            #pragma unroll
            for (int f = 0; f < 8; ++f)
                b[f] = *reinterpret_cast<const short8*>(
                    &p.W2p[((size_t)k8 * 512 + colw + (f << 4) + l16) << 3]);
            #pragma unroll
            for (int m = 0; m < 4; ++m) {
                const short8 a = *reinterpret_cast<const short8*>(
                    &As[(m * 16 + l16) * 72 + (kt << 5) + (quad << 3)]);
                #pragma unroll
                for (int f = 0; f < 8; ++f)
                    acc[m][f] = __builtin_amdgcn_mfma_f32_16x16x32_bf16(a, b[f], acc[m][f], 0, 0, 0);
            }
        }
    }
    #pragma unroll
    for (int m = 0; m < 4; ++m)
        #pragma unroll
        for (int f = 0; f < 8; ++f) {
            const int col = colw + (f << 4) + l16;
            const float bias = p.b2[col];
            #pragma unroll
            for (int r = 0; r < 4; ++r) {
                const int row = m * 16 + quad * 4 + r;
                Hs[row * HS_STRIDE + col] = f2bf(fast_tanh(acc[m][f][r] + bias));
            }
        }
    __syncthreads();

    // ========= phase B: f = h2 @ W3 + b3 ; RK4 state epilogue (A from LDS) =====
    floatx4 a3[4][2];
    #pragma unroll
    for (int m = 0; m < 4; ++m)
        #pragma unroll
        for (int f = 0; f < 2; ++f) { floatx4 zz = {0.f,0.f,0.f,0.f}; a3[m][f] = zz; }
    #pragma unroll 4
    for (int kt = 0; kt < 16; ++kt) {
        const int k8 = (kt << 2) + quad;
        short8 b[2];
        #pragma unroll
        for (int f = 0; f < 2; ++f)
            b[f] = *reinterpret_cast<const short8*>(
                &p.W3p[((size_t)k8 * 128 + (wave << 5) + (f << 4) + l16) << 3]);
        #pragma unroll
        for (int m = 0; m < 4; ++m) {
            const short8 a = *reinterpret_cast<const short8*>(
                &Hs[(m * 16 + l16) * HS_STRIDE + (kt << 5) + (quad << 3)]);
            #pragma unroll
            for (int f = 0; f < 2; ++f)
                a3[m][f] = __builtin_amdgcn_mfma_f32_16x16x32_bf16(a, b[f], a3[m][f], 0, 0, 0);
        }
    }
    #pragma unroll
    for (int m = 0; m < 4; ++m)
        #pragma unroll
        for (int f = 0; f < 2; ++f) {
            const int col = (wave << 5) + (f << 4) + l16;
            const float bias = p.b3[col];
            #pragma unroll
            for (int r = 0; r < 4; ++r) {
                const int row = row0 + m * 16 + quad * 4 + r;
                const size_t idxN = (size_t)row * 128 + col;
                const float x = a3[m][f][r] + bias;
                const float a = p.wrk * x + (p.s0 ? 0.0f : p.accf[idxN]);
                if (p.s3) {
                    const float zn = p.z[idxN] + a;       // z += dt/6 * sum(k)
                    p.z[idxN]  = zn;
                    p.zs[idxN] = f2bf(zn);                // next step s0 input
                } else {
                    p.accf[idxN] = a;
                    p.zs[idxN]   = f2bf(p.z[idxN] + p.cnext * x);
                }
            }
        }
    __syncthreads();

    // ============ phase C: Hs <- g2 = g3 * (1 - h2^2)  (in-place) ==============
    {
        const int r  = tid >> 3;
        const int c8 = (tid & 7) << 3;
        #pragma unroll
        for (int i = 0; i < 2; ++i) {
            const int rr = r + (i << 5);
            const size_t gbase = (size_t)(row0 + rr) * 512;
            #pragma unroll
            for (int j = 0; j < 8; ++j) {
                const int cc = c8 + (j << 6);
                short8 hv = *reinterpret_cast<const short8*>(&Hs[rr * HS_STRIDE + cc]);
                const short8 gv = *reinterpret_cast<const short8*>(&p.g3[gbase + cc]);
                short8 ov;
                #pragma unroll
                for (int e = 0; e < 8; ++e) {
                    const float h = bf2f((unsigned short)hv[e]);
                    const float g = bf2f((unsigned short)gv[e]);
                    ov[e] = (short)f2bf(g * (1.0f - h * h));
                }
                *reinterpret_cast<short8*>(&Hs[rr * HS_STRIDE + cc]) = ov;
            }
        }
    }
    __syncthreads();

    // ======== phase D: Hs <- g2 @ W2^T (A from LDS, overwrite after drain) =====
    #pragma unroll
    for (int m = 0; m < 4; ++m)
        #pragma unroll
        for (int f = 0; f < 8; ++f) { floatx4 zz = {0.f,0.f,0.f,0.f}; acc[m][f] = zz; }
    #pragma unroll 2
    for (int kt = 0; kt < 16; ++kt) {
        const int k8 = (kt << 2) + quad;
        short8 b[8];
        #pragma unroll
        for (int f = 0; f < 8; ++f)
            b[f] = *reinterpret_cast<const short8*>(
                &p.W2Tp[((size_t)k8 * 512 + colw + (f << 4) + l16) << 3]);
        #pragma unroll
        for (int m = 0; m < 4; ++m) {
            const short8 a = *reinterpret_cast<const short8*>(
                &Hs[(m * 16 + l16) * HS_STRIDE + (kt << 5) + (quad << 3)]);
            #pragma unroll
            for (int f = 0; f < 8; ++f)
                acc[m][f] = __builtin_amdgcn_mfma_f32_16x16x32_bf16(a, b[f], acc[m][f], 0, 0, 0);
        }
    }
    __syncthreads();   // all g2 reads done before in-place overwrite
    #pragma unroll
    for (int m = 0; m < 4; ++m)
        #pragma unroll
        for (int f = 0; f < 8; ++f) {
            const int col = colw + (f << 4) + l16;
            #pragma unroll
            for (int r = 0; r < 4; ++r) {
                const int row = m * 16 + quad * 4 + r;
                Hs[row * HS_STRIDE + col] = f2bf(acc[m][f][r]);
            }
        }
    __syncthreads();

    // ====== phase D2: Hs *= (1 - h1^2)  (vectorized h1 reads) => g1 ============
    {
        const int r  = tid >> 3;
        const int c8 = (tid & 7) << 3;
        #pragma unroll
        for (int i = 0; i < 2; ++i) {
            const int rr = r + (i << 5);
            const size_t gbase = (size_t)(row0 + rr) * 512;
            #pragma unroll
            for (int j = 0; j < 8; ++j) {
                const int cc = c8 + (j << 6);
                short8 xv = *reinterpret_cast<const short8*>(&Hs[rr * HS_STRIDE + cc]);
                const short8 hv = *reinterpret_cast<const short8*>(&p.A[gbase + cc]);
                short8 ov;
                #pragma unroll
                for (int e = 0; e < 8; ++e) {
                    const float x = bf2f((unsigned short)xv[e]);
                    const float h = bf2f((unsigned short)hv[e]);
                    ov[e] = (short)f2bf(x * (1.0f - h * h));
                }
                *reinterpret_cast<short8*>(&Hs[rr * HS_STRIDE + cc]) = ov;
            }
        }
    }
    __syncthreads();

    // ====== phase E: vJ = g1 @ W1z^T ; div = rowsum(vJ*v) ; accd/lp ============
    floatx4 ad[8];
    #pragma unroll
    for (int f = 0; f < 8; ++f) { floatx4 zz = {0.f,0.f,0.f,0.f}; ad[f] = zz; }
    #pragma unroll 4
    for (int kt = 0; kt < 16; ++kt) {
        const int k8 = (kt << 2) + quad;
        const short8 a = *reinterpret_cast<const short8*>(
            &Hs[((wave << 4) + l16) * HS_STRIDE + (kt << 5) + (quad << 3)]);
        #pragma unroll
        for (int f = 0; f < 8; ++f) {
            const short8 b = *reinterpret_cast<const short8*>(
                &p.W1Tp[((size_t)k8 * 128 + (f << 4) + l16) << 3]);
            ad[f] = __builtin_amdgcn_mfma_f32_16x16x32_bf16(a, b, ad[f], 0, 0, 0);
        }
    }
    #pragma unroll
    for (int r = 0; r < 4; ++r) {
        const int row = row0 + (wave << 4) + quad * 4 + r;
        float part = 0.0f;
        #pragma unroll
        for (int f = 0; f < 8; ++f)
            part += ad[f][r] * p.v[(size_t)row * 128 + (f << 4) + l16];
        part += __shfl_xor(part, 1);
        part += __shfl_xor(part, 2);
        part += __shfl_xor(part, 4);
        part += __shfl_xor(part, 8);
        if (l16 == 0) {
            const float a = p.wrk * (-part) + (p.s0 ? 0.0f : p.accd[row]);
            if (p.s3) p.lp[row] += a;
            else      p.accd[row] = a;
        }
    }
}

// out[b] = lp[b] - 0.5*||z||^2 - 0.5*128*log(2*pi)
__global__ void final_k(const float* __restrict__ z, const float* __restrict__ lp,
                        float* __restrict__ out) {
    const int tid = threadIdx.x;
    const int row = blockIdx.x * 16 + (tid >> 4);
    const int l16 = tid & 15;
    const float4* zr = (const float4*)&z[(size_t)row * 128 + (l16 << 3)];
    float4 a = zr[0], b = zr[1];
    float s = a.x*a.x + a.y*a.y + a.z*a.z + a.w*a.w
            + b.x*b.x + b.y*b.y + b.z*b.z + b.w*b.w;
    s += __shfl_xor(s, 1);
    s += __shfl_xor(s, 2);
    s += __shfl_xor(s, 4);
    s += __shfl_xor(s, 8);
    if (l16 == 0) out[row] = lp[row] - 0.5f * s - 117.6241322501981f;
}

extern "C" void kernel_launch(void* const* d_in, const int* in_sizes, int n_in,
                              void* d_out, int out_size, void* d_ws, size_t ws_size,
                              hipStream_t stream) {
    (void)n_in; (void)out_size;
    const float* x  = (const float*)d_in[0];
    const float* v  = (const float*)d_in[1];
    const float* W1 = (const float*)d_in[2];
    const float* b1 = (const float*)d_in[3];
    const float* W2 = (const float*)d_in[4];
    const float* b2 = (const float*)d_in[5];
    const float* W3 = (const float*)d_in[6];
    const float* b3 = (const float*)d_in[7];
    float* out = (float*)d_out;
    const int B = in_sizes[0] / DIMV;   // 65536

    auto al = [](size_t s) { return (s + 255) & ~(size_t)255; };
    auto need_for = [&](size_t C) {
        size_t s = 0;
        s += al(C * DIMV * 4);       // z
        s += al(C * DIMV * 4);       // accf
        s += al(C * DIMV * 2);       // zs
        s += al(C * 4);              // lp
        s += al(C * 4);              // accd
        s += al(C * HIDV * 2) * 2;   // h1, g3
        s += al(128 * 512 * 2) * 4 + al(512 * 512 * 2) * 2; // packed weights
        return s;
    };
    // Largest power-of-two chunk (<=32768 rows: keeps working set inside 256MB L3)
    // that fits ws_size.
    size_t C = 32768;
    while (C > 1024 && need_for(C) > ws_size) C >>= 1;
    if (need_for(C) > ws_size) return;  // cannot run safely in this workspace

    char* w = (char*)d_ws;
    auto alloc = [&](size_t bytes) { char* p = w; w += al(bytes); return p; };
    float* z    = (float*)alloc(C * DIMV * 4);
    float* accf = (float*)alloc(C * DIMV * 4);
    unsigned short* zs = (unsigned short*)alloc(C * DIMV * 2);
    float* lp   = (float*)alloc(C * 4);
    float* accd = (float*)alloc(C * 4);
    unsigned short* h1 = (unsigned short*)alloc(C * HIDV * 2);
    unsigned short* g3 = (unsigned short*)alloc(C * HIDV * 2);
    unsigned short* W1zp  = (unsigned short*)alloc(128 * 512 * 2);
    unsigned short* W3p   = (unsigned short*)alloc(512 * 128 * 2);
    unsigned short* W1zTp = (unsigned short*)alloc(512 * 128 * 2);
    unsigned short* W3Tp  = (unsigned short*)alloc(128 * 512 * 2);
    unsigned short* W2p   = (unsigned short*)alloc(512 * 512 * 2);
    unsigned short* W2Tp  = (unsigned short*)alloc(512 * 512 * 2);

    auto pack = [&](const float* src, unsigned short* dst, int K, int N, int ld, int tr) {
        pack_kernel<<<dim3((K * N + 255) / 256), dim3(256), 0, stream>>>(src, dst, K, N, ld, tr);
    };
    pack(W1, W1zp,  128, 512, 512, 0);
    pack(W2, W2p,   512, 512, 512, 0);
    pack(W3, W3p,   512, 128, 128, 0);
    pack(W2, W2Tp,  512, 512, 512, 1);
    pack(W1, W1zTp, 512, 128, 512, 1);
    pack(W3, W3Tp,  128, 512, 128, 1);

    const float dt = 1.0f / 32.0f;
    const float cs[4]  = {0.0f, 0.5f * dt, 0.5f * dt, dt};
    const float wr4[4] = {dt / 6.0f, dt / 3.0f, dt / 3.0f, dt / 6.0f};
    const int GM128 = (int)C / 128;
    const int GMF   = (int)C / 64;

    for (int c0 = 0; c0 < B; c0 += (int)C) {
        const float* xc = x + (size_t)c0 * DIMV;
        const float* vc = v + (size_t)c0 * DIMV;

        init_k<<<dim3(((int)C * DIMV + 255) / 256), 256, 0, stream>>>(
            xc, z, zs, lp, (int)C * DIMV, (int)C);

        {   // g3 = v @ W3^T  (once per chunk)
            GArgs p{};
            p.v = vc; p.Wp = W3Tp; p.out0 = g3;
            gemm_k<128, 512, 4, PROD_V, EPI_G3><<<dim3(GM128, 2), 256, 0, stream>>>(p);
        }

        for (int step = 0; step < 32; ++step) {
            const float t0 = (float)step * dt;
            for (int s = 0; s < 4; ++s) {
                // K1: h1 = tanh(zs @ W1z + t*w1t + b1)
                GArgs p{};
                p.t = t0 + cs[s];
                p.A = zs; p.Wp = W1zp; p.bias = b1; p.w1t = W1 + 128 * 512; p.out0 = h1;
                gemm_k<128, 512, 4, PROD_BF16, EPI_H1><<<dim3(GM128, 2), 256, 0, stream>>>(p);

                // KBC: fused h2 / f / g2 / g1 / div
                FArgs q{};
                q.A = h1; q.W2p = W2p; q.W3p = W3p; q.W2Tp = W2Tp; q.W1Tp = W1zTp;
                q.g3 = g3; q.v = vc; q.b2 = b2; q.b3 = b3;
                q.z = z; q.accf = accf; q.zs = zs; q.accd = accd; q.lp = lp;
                q.cnext = (s < 3) ? cs[s + 1] : 0.0f;
                q.wrk = wr4[s];
                q.s0 = (s == 0); q.s3 = (s == 3);
                kbc_k<<<dim3(GMF), 256, 0, stream>>>(q);
            }
        }

        final_k<<<dim3((int)C / 16), 256, 0, stream>>>(z, lp, out + c0);
    }
}

// Round 2
// 22033.005 us; speedup vs baseline: 1.7556x; 1.1823x over previous
//
#include <hip/hip_runtime.h>

// FFJORD density on MI355X (gfx950). B=65536 rows, DIM=128, HID=512, 32 RK4 steps x 4 evals.
// Round 4: occupancy + algebraic restructure of the fused kernel.
//  - kbc_k now 512 threads / 8 waves, __launch_bounds__(512,4) -> 2 blocks/CU, 4 waves/SIMD
//    (was 2/SIMD). Per-wave acc shrinks to 4x4 frags (64 regs) to fit the 128-reg cap.
//  - div trick: div[r] = sum_k g1'[r,k]*(1-h1^2)*u[r,k] with u = v @ W1z precomputed ONCE
//    per chunk (like g3). Eliminates the phase-E GEMM, all W1z^T reads, and the D2 pass.
//  - phase A stages next h1 k-slice into regs before compute (latency hidden under MFMA).
//  - HS_STRIDE 524 -> 520 shorts: rows 16B-aligned for ds_read_b128, still conflict-free
//    (bank shift 4/row -> 8 lanes/bank = the 1KB/8cy floor).
// Per stage: K1 (h1 GEMM) + kbc_k { A: h2=tanh(h1@W2+b2)->LDS; B: f=h2@W3+b3 + RK4 state;
//   C: Hs<-g2=g3*(1-h2^2); D: Hs<-g2@W2^T; E: div=rowsum(Hs*(1-h1^2)*u) streaming }.

#define DIMV 128
#define HIDV 512
#define HS_STRIDE 520

typedef float  floatx4 __attribute__((ext_vector_type(4)));
typedef short  short8  __attribute__((ext_vector_type(8)));

static __device__ __forceinline__ unsigned short f2bf(float x) {
    union { float f; unsigned int u; } c; c.f = x;
    unsigned int u = c.u;
    u += 0x7FFFu + ((u >> 16) & 1u);   // round-to-nearest-even
    return (unsigned short)(u >> 16);
}
static __device__ __forceinline__ float bf2f(unsigned short h) {
    union { unsigned int u; float f; } c; c.u = ((unsigned int)h) << 16;
    return c.f;
}
static __device__ __forceinline__ float fast_tanh(float x) {
    x = fminf(8.0f, fmaxf(-8.0f, x));
    float e = exp2f(x * 2.8853900817779268f);            // exp(2x)
    return (e - 1.0f) * __builtin_amdgcn_rcpf(e + 1.0f); // (e-1)/(e+1)
}

// ---- weight packing: dst[(k>>3)*N*8 + n*8 + (k&7)] = bf16(W[k][n]) ------------
__global__ void pack_kernel(const float* __restrict__ src, unsigned short* __restrict__ dst,
                            int K, int N, int ld, int transpose) {
    int i = blockIdx.x * 256 + threadIdx.x;
    if (i >= K * N) return;
    int j  = i & 7;
    int n  = (i >> 3) % N;
    int k8 = (i >> 3) / N;
    int k  = k8 * 8 + j;
    float v = transpose ? src[n * ld + k] : src[k * ld + n];
    dst[i] = f2bf(v);
}

// ---- per-chunk init: z = x (fp32), zs = bf16(x), lp = 0 -----------------------
__global__ void init_k(const float* __restrict__ x, float* __restrict__ z,
                       unsigned short* __restrict__ zs, float* __restrict__ lp,
                       int n, int nrows) {
    int i = blockIdx.x * 256 + threadIdx.x;
    if (i < n) { float val = x[i]; z[i] = val; zs[i] = f2bf(val); }
    if (i < nrows) lp[i] = 0.0f;
}

#define PROD_BF16 0
#define PROD_V    1
#define EPI_H1   0
#define EPI_G3   1

struct GArgs {
    const float* v;            // fp32 probe (chunk ptr) [C,128]
    const unsigned short* A;   // bf16 A input
    const unsigned short* Wp;  // packed bf16 weights
    const float* bias;
    const float* w1t;          // W1 row 128 (t coefficients)
    unsigned short* out0;      // bf16 output
    float t;
};

// K1 / g3 / u producer. Tile: 128 rows x (NFRAG*64) cols per WG; 4 waves.
template<int KDIM, int NDIM, int NFRAG, int PROD, int EPI>
__global__ __launch_bounds__(256, 2) void gemm_k(GArgs p) {
    __shared__ __align__(16) unsigned short As[128 * 72];
    const int tid  = threadIdx.x;
    const int wave = tid >> 6, lane = tid & 63;
    const int quad = lane >> 4, l16 = lane & 15;
    const int row0 = blockIdx.x * 128;
    const int colw = blockIdx.y * (NFRAG * 64) + wave * (NFRAG * 16);

    floatx4 acc[8][NFRAG];
    #pragma unroll
    for (int m = 0; m < 8; ++m)
        #pragma unroll
        for (int f = 0; f < NFRAG; ++f) {
            floatx4 zz = {0.f, 0.f, 0.f, 0.f};
            acc[m][f] = zz;
        }

    for (int k0 = 0; k0 < KDIM; k0 += 64) {
        __syncthreads();
        {   // ---- stage A chunk: 128 rows x 64 k into LDS ----
            const int r  = tid >> 3;
            const int cc = (tid & 7) << 3;
            #pragma unroll
            for (int i = 0; i < 4; ++i) {
                const int rr = r + (i << 5);
                const size_t base = (size_t)(row0 + rr) * KDIM + k0 + cc;
                if constexpr (PROD == PROD_BF16) {
                    const short8 val = *reinterpret_cast<const short8*>(&p.A[base]);
                    *reinterpret_cast<short8*>(&As[rr * 72 + cc]) = val;
                } else { // PROD_V: fp32 -> bf16 on the fly
                    float vals[8];
                    *(float4*)&vals[0] = *(const float4*)&p.v[base];
                    *(float4*)&vals[4] = *(const float4*)&p.v[base + 4];
                    short8 sv;
                    #pragma unroll
                    for (int j = 0; j < 8; ++j) sv[j] = (short)f2bf(vals[j]);
                    *reinterpret_cast<short8*>(&As[rr * 72 + cc]) = sv;
                }
            }
        }
        __syncthreads();
        #pragma unroll
        for (int kt = 0; kt < 2; ++kt) {
            const int k8 = (k0 >> 3) + (kt << 2) + quad;
            short8 b[NFRAG];
            #pragma unroll
            for (int f = 0; f < NFRAG; ++f)
                b[f] = *reinterpret_cast<const short8*>(
                    &p.Wp[((size_t)k8 * NDIM + colw + (f << 4) + l16) << 3]);
            #pragma unroll
            for (int m = 0; m < 8; ++m) {
                const short8 a = *reinterpret_cast<const short8*>(
                    &As[(m * 16 + l16) * 72 + (kt << 5) + (quad << 3)]);
                #pragma unroll
                for (int f = 0; f < NFRAG; ++f)
                    acc[m][f] = __builtin_amdgcn_mfma_f32_16x16x32_bf16(a, b[f], acc[m][f], 0, 0, 0);
            }
        }
    }

    #pragma unroll
    for (int m = 0; m < 8; ++m)
        #pragma unroll
        for (int f = 0; f < NFRAG; ++f) {
            const int col = colw + (f << 4) + l16;
            float bias = 0.0f;
            if constexpr (EPI == EPI_H1) bias = p.bias[col] + p.t * p.w1t[col];
            #pragma unroll
            for (int r = 0; r < 4; ++r) {
                const int row = row0 + m * 16 + quad * 4 + r;
                const size_t idxN = (size_t)row * NDIM + col;
                float x = acc[m][f][r] + bias;
                if constexpr (EPI == EPI_H1) p.out0[idxN] = f2bf(fast_tanh(x));
                else                         p.out0[idxN] = f2bf(x);
            }
        }
}

// ---- fused stage kernel: h2 / f / g2 / g1' / div ------------------------------
struct FArgs {
    const unsigned short* A;      // h1 bf16 [C,512]
    const unsigned short* W2p;    // packed W2    (K=512,N=512)
    const unsigned short* W3p;    // packed W3    (K=512,N=128)
    const unsigned short* W2Tp;   // packed W2^T  (K=512,N=512)
    const unsigned short* g3;     // bf16 [C,512]
    const unsigned short* u;      // bf16 [C,512]  u = v @ W1z (per chunk)
    const float* b2;
    const float* b3;
    float* z;
    float* accf;
    unsigned short* zs;
    float* accd;
    float* lp;
    float cnext, wrk;
    int s0, s3;
};

__global__ __launch_bounds__(512, 4) void kbc_k(FArgs p) {
    __shared__ __align__(16) unsigned short As[64 * 72];        //  9.0 KB h1 staging
    __shared__ __align__(16) unsigned short Hs[64 * HS_STRIDE]; // 65.0 KB h2/g2/g1' panel
    const int tid  = threadIdx.x;
    const int wave = tid >> 6, lane = tid & 63;
    const int quad = lane >> 4, l16 = lane & 15;
    const int row0 = blockIdx.x * 64;
    const int colw = wave << 6;   // phases A/D: 64 cols per wave

    // ================= phase A: h2 = tanh(h1 @ W2 + b2) -> Hs =================
    floatx4 acc[4][4];
    #pragma unroll
    for (int m = 0; m < 4; ++m)
        #pragma unroll
        for (int f = 0; f < 4; ++f) { floatx4 zz = {0.f,0.f,0.f,0.f}; acc[m][f] = zz; }

    const int sr = tid >> 3;            // 0..63
    const int sc = (tid & 7) << 3;      // 0..56
    const unsigned short* Abase = p.A + (size_t)(row0 + sr) * 512 + sc;
    short8 st = *reinterpret_cast<const short8*>(Abase);   // preload k0=0

    for (int k0 = 0; k0 < 512; k0 += 64) {
        __syncthreads();
        *reinterpret_cast<short8*>(&As[sr * 72 + sc]) = st;
        if (k0 + 64 < 512)
            st = *reinterpret_cast<const short8*>(Abase + k0 + 64);  // in flight under MFMA
        __syncthreads();
        #pragma unroll
        for (int kt = 0; kt < 2; ++kt) {
            const int k8 = (k0 >> 3) + (kt << 2) + quad;
            short8 b[4];
            #pragma unroll
            for (int f = 0; f < 4; ++f)
                b[f] = *reinterpret_cast<const short8*>(
                    &p.W2p[((size_t)k8 * 512 + colw + (f << 4) + l16) << 3]);
            #pragma unroll
            for (int m = 0; m < 4; ++m) {
                const short8 a = *reinterpret_cast<const short8*>(
                    &As[(m * 16 + l16) * 72 + (kt << 5) + (quad << 3)]);
                #pragma unroll
                for (int f = 0; f < 4; ++f)
                    acc[m][f] = __builtin_amdgcn_mfma_f32_16x16x32_bf16(a, b[f], acc[m][f], 0, 0, 0);
            }
        }
    }
    #pragma unroll
    for (int m = 0; m < 4; ++m)
        #pragma unroll
        for (int f = 0; f < 4; ++f) {
            const int col = colw + (f << 4) + l16;
            const float bias = p.b2[col];
            #pragma unroll
            for (int r = 0; r < 4; ++r) {
                const int row = m * 16 + quad * 4 + r;
                Hs[row * HS_STRIDE + col] = f2bf(fast_tanh(acc[m][f][r] + bias));
            }
        }
    __syncthreads();

    // ========= phase B: f = h2 @ W3 + b3 ; RK4 state epilogue (A from LDS) =====
    {
        const int mB   = (wave & 3) << 4;   // 16-row group
        const int half = (wave >> 2) << 6;  // col half 0/64
        floatx4 a3[4];
        #pragma unroll
        for (int f = 0; f < 4; ++f) { floatx4 zz = {0.f,0.f,0.f,0.f}; a3[f] = zz; }
        #pragma unroll 4
        for (int kt = 0; kt < 16; ++kt) {
            const int k8 = (kt << 2) + quad;
            short8 b[4];
            #pragma unroll
            for (int f = 0; f < 4; ++f)
                b[f] = *reinterpret_cast<const short8*>(
                    &p.W3p[((size_t)k8 * 128 + half + (f << 4) + l16) << 3]);
            const short8 a = *reinterpret_cast<const short8*>(
                &Hs[(mB + l16) * HS_STRIDE + (kt << 5) + (quad << 3)]);
            #pragma unroll
            for (int f = 0; f < 4; ++f)
                a3[f] = __builtin_amdgcn_mfma_f32_16x16x32_bf16(a, b[f], a3[f], 0, 0, 0);
        }
        #pragma unroll
        for (int f = 0; f < 4; ++f) {
            const int col = half + (f << 4) + l16;
            const float bias = p.b3[col];
            #pragma unroll
            for (int r = 0; r < 4; ++r) {
                const int row = row0 + mB + quad * 4 + r;
                const size_t idxN = (size_t)row * 128 + col;
                const float x = a3[f][r] + bias;
                const float a = p.wrk * x + (p.s0 ? 0.0f : p.accf[idxN]);
                if (p.s3) {
                    const float zn = p.z[idxN] + a;       // z += dt/6 * sum(k)
                    p.z[idxN]  = zn;
                    p.zs[idxN] = f2bf(zn);                // next step s0 input
                } else {
                    p.accf[idxN] = a;
                    p.zs[idxN]   = f2bf(p.z[idxN] + p.cnext * x);
                }
            }
        }
    }
    __syncthreads();

    // ============ phase C: Hs <- g2 = g3 * (1 - h2^2)  (in-place) ==============
    {
        const size_t gbase = (size_t)(row0 + sr) * 512;
        #pragma unroll
        for (int j = 0; j < 8; ++j) {
            const int cc = sc + (j << 6);
            short8 hv = *reinterpret_cast<const short8*>(&Hs[sr * HS_STRIDE + cc]);
            const short8 gv = *reinterpret_cast<const short8*>(&p.g3[gbase + cc]);
            short8 ov;
            #pragma unroll
            for (int e = 0; e < 8; ++e) {
                const float h = bf2f((unsigned short)hv[e]);
                const float g = bf2f((unsigned short)gv[e]);
                ov[e] = (short)f2bf(g * (1.0f - h * h));
            }
            *reinterpret_cast<short8*>(&Hs[sr * HS_STRIDE + cc]) = ov;
        }
    }
    __syncthreads();

    // ======== phase D: Hs <- g2 @ W2^T (A from LDS, overwrite after drain) =====
    #pragma unroll
    for (int m = 0; m < 4; ++m)
        #pragma unroll
        for (int f = 0; f < 4; ++f) { floatx4 zz = {0.f,0.f,0.f,0.f}; acc[m][f] = zz; }
    #pragma unroll 2
    for (int kt = 0; kt < 16; ++kt) {
        const int k8 = (kt << 2) + quad;
        short8 b[4];
        #pragma unroll
        for (int f = 0; f < 4; ++f)
            b[f] = *reinterpret_cast<const short8*>(
                &p.W2Tp[((size_t)k8 * 512 + colw + (f << 4) + l16) << 3]);
        #pragma unroll
        for (int m = 0; m < 4; ++m) {
            const short8 a = *reinterpret_cast<const short8*>(
                &Hs[(m * 16 + l16) * HS_STRIDE + (kt << 5) + (quad << 3)]);
            #pragma unroll
            for (int f = 0; f < 4; ++f)
                acc[m][f] = __builtin_amdgcn_mfma_f32_16x16x32_bf16(a, b[f], acc[m][f], 0, 0, 0);
        }
    }
    __syncthreads();   // all g2 reads done before in-place overwrite
    #pragma unroll
    for (int m = 0; m < 4; ++m)
        #pragma unroll
        for (int f = 0; f < 4; ++f) {
            const int col = colw + (f << 4) + l16;
            #pragma unroll
            for (int r = 0; r < 4; ++r) {
                const int row = m * 16 + quad * 4 + r;
                Hs[row * HS_STRIDE + col] = f2bf(acc[m][f][r]);
            }
        }
    __syncthreads();

    // ====== phase E: div = rowsum(g1' * (1-h1^2) * u) ; accd/lp (streaming) ====
    {
        const size_t gbase = (size_t)(row0 + sr) * 512;
        float s = 0.0f;
        #pragma unroll
        for (int j = 0; j < 8; ++j) {
            const int cc = sc + (j << 6);
            const short8 xv = *reinterpret_cast<const short8*>(&Hs[sr * HS_STRIDE + cc]);
            const short8 hv = *reinterpret_cast<const short8*>(&p.A[gbase + cc]);
            const short8 uv = *reinterpret_cast<const short8*>(&p.u[gbase + cc]);
            #pragma unroll
            for (int e = 0; e < 8; ++e) {
                const float x = bf2f((unsigned short)xv[e]);
                const float h = bf2f((unsigned short)hv[e]);
                const float uu = bf2f((unsigned short)uv[e]);
                s += x * (1.0f - h * h) * uu;
            }
        }
        s += __shfl_xor(s, 1);
        s += __shfl_xor(s, 2);
        s += __shfl_xor(s, 4);
        if ((tid & 7) == 0) {
            const int row = row0 + sr;
            const float a = p.wrk * (-s) + (p.s0 ? 0.0f : p.accd[row]);
            if (p.s3) p.lp[row] += a;
            else      p.accd[row] = a;
        }
    }
}

// out[b] = lp[b] - 0.5*||z||^2 - 0.5*128*log(2*pi)
__global__ void final_k(const float* __restrict__ z, const float* __restrict__ lp,
                        float* __restrict__ out) {
    const int tid = threadIdx.x;
    const int row = blockIdx.x * 16 + (tid >> 4);
    const int l16 = tid & 15;
    const float4* zr = (const float4*)&z[(size_t)row * 128 + (l16 << 3)];
    float4 a = zr[0], b = zr[1];
    float s = a.x*a.x + a.y*a.y + a.z*a.z + a.w*a.w
            + b.x*b.x + b.y*b.y + b.z*b.z + b.w*b.w;
    s += __shfl_xor(s, 1);
    s += __shfl_xor(s, 2);
    s += __shfl_xor(s, 4);
    s += __shfl_xor(s, 8);
    if (l16 == 0) out[row] = lp[row] - 0.5f * s - 117.6241322501981f;
}

extern "C" void kernel_launch(void* const* d_in, const int* in_sizes, int n_in,
                              void* d_out, int out_size, void* d_ws, size_t ws_size,
                              hipStream_t stream) {
    (void)n_in; (void)out_size;
    const float* x  = (const float*)d_in[0];
    const float* v  = (const float*)d_in[1];
    const float* W1 = (const float*)d_in[2];
    const float* b1 = (const float*)d_in[3];
    const float* W2 = (const float*)d_in[4];
    const float* b2 = (const float*)d_in[5];
    const float* W3 = (const float*)d_in[6];
    const float* b3 = (const float*)d_in[7];
    float* out = (float*)d_out;
    const int B = in_sizes[0] / DIMV;   // 65536

    auto al = [](size_t s) { return (s + 255) & ~(size_t)255; };
    auto need_for = [&](size_t C) {
        size_t s = 0;
        s += al(C * DIMV * 4);       // z
        s += al(C * DIMV * 4);       // accf
        s += al(C * DIMV * 2);       // zs
        s += al(C * 4);              // lp
        s += al(C * 4);              // accd
        s += al(C * HIDV * 2) * 3;   // h1, g3, u
        s += al(128 * 512 * 2) * 3 + al(512 * 512 * 2) * 2; // packed weights
        return s;
    };
    size_t C = 32768;
    while (C > 1024 && need_for(C) > ws_size) C >>= 1;
    if (need_for(C) > ws_size) return;  // cannot run safely in this workspace

    char* w = (char*)d_ws;
    auto alloc = [&](size_t bytes) { char* p = w; w += al(bytes); return p; };
    float* z    = (float*)alloc(C * DIMV * 4);
    float* accf = (float*)alloc(C * DIMV * 4);
    unsigned short* zs = (unsigned short*)alloc(C * DIMV * 2);
    float* lp   = (float*)alloc(C * 4);
    float* accd = (float*)alloc(C * 4);
    unsigned short* h1 = (unsigned short*)alloc(C * HIDV * 2);
    unsigned short* g3 = (unsigned short*)alloc(C * HIDV * 2);
    unsigned short* u  = (unsigned short*)alloc(C * HIDV * 2);
    unsigned short* W1zp  = (unsigned short*)alloc(128 * 512 * 2);
    unsigned short* W3p   = (unsigned short*)alloc(512 * 128 * 2);
    unsigned short* W3Tp  = (unsigned short*)alloc(128 * 512 * 2);
    unsigned short* W2p   = (unsigned short*)alloc(512 * 512 * 2);
    unsigned short* W2Tp  = (unsigned short*)alloc(512 * 512 * 2);

    auto pack = [&](const float* src, unsigned short* dst, int K, int N, int ld, int tr) {
        pack_kernel<<<dim3((K * N + 255) / 256), dim3(256), 0, stream>>>(src, dst, K, N, ld, tr);
    };
    pack(W1, W1zp,  128, 512, 512, 0);
    pack(W2, W2p,   512, 512, 512, 0);
    pack(W3, W3p,   512, 128, 128, 0);
    pack(W2, W2Tp,  512, 512, 512, 1);
    pack(W3, W3Tp,  128, 512, 128, 1);

    const float dt = 1.0f / 32.0f;
    const float cs[4]  = {0.0f, 0.5f * dt, 0.5f * dt, dt};
    const float wr4[4] = {dt / 6.0f, dt / 3.0f, dt / 3.0f, dt / 6.0f};
    const int GM128 = (int)C / 128;
    const int GMF   = (int)C / 64;

    for (int c0 = 0; c0 < B; c0 += (int)C) {
        const float* xc = x + (size_t)c0 * DIMV;
        const float* vc = v + (size_t)c0 * DIMV;

        init_k<<<dim3(((int)C * DIMV + 255) / 256), 256, 0, stream>>>(
            xc, z, zs, lp, (int)C * DIMV, (int)C);

        {   // g3 = v @ W3^T ; u = v @ W1z  (once per chunk)
            GArgs p{};
            p.v = vc; p.Wp = W3Tp; p.out0 = g3;
            gemm_k<128, 512, 4, PROD_V, EPI_G3><<<dim3(GM128, 2), 256, 0, stream>>>(p);
            p.Wp = W1zp; p.out0 = u;
            gemm_k<128, 512, 4, PROD_V, EPI_G3><<<dim3(GM128, 2), 256, 0, stream>>>(p);
        }

        for (int step = 0; step < 32; ++step) {
            const float t0 = (float)step * dt;
            for (int s = 0; s < 4; ++s) {
                // K1: h1 = tanh(zs @ W1z + t*w1t + b1)
                GArgs p{};
                p.t = t0 + cs[s];
                p.A = zs; p.Wp = W1zp; p.bias = b1; p.w1t = W1 + 128 * 512; p.out0 = h1;
                gemm_k<128, 512, 4, PROD_BF16, EPI_H1><<<dim3(GM128, 2), 256, 0, stream>>>(p);

                // KBC: fused h2 / f / g2 / g1' / div
                FArgs q{};
                q.A = h1; q.W2p = W2p; q.W3p = W3p; q.W2Tp = W2Tp;
                q.g3 = g3; q.u = u; q.b2 = b2; q.b3 = b3;
                q.z = z; q.accf = accf; q.zs = zs; q.accd = accd; q.lp = lp;
                q.cnext = (s < 3) ? cs[s + 1] : 0.0f;
                q.wrk = wr4[s];
                q.s0 = (s == 0); q.s3 = (s == 3);
                kbc_k<<<dim3(GMF), 512, 0, stream>>>(q);
            }
        }

        final_k<<<dim3((int)C / 16), 256, 0, stream>>>(z, lp, out + c0);
    }
}